// Round 5
// baseline (122.437 us; speedup 1.0000x reference)
//
#include <hip/hip_runtime.h>
#include <hip/hip_bf16.h>
#include <math.h>

// Problem constants (fixed shape)
#define T_ 1024
#define H_ 1024
#define I_ 2048
#define E_ 8
#define NSLOT 2048

// GEMM tiling
#define BM 128
#define BN 32
#define BK 32
#define NCHUNK_CAP 24               // sum of ceil(cnt_e/BM) <= E-1 + NSLOT/BM = 23
#define SPLITK2 2                    // gemm2 split-K (I=2048 -> 2x1024)

typedef __attribute__((ext_vector_type(8))) short bf16x8;
typedef __attribute__((ext_vector_type(4))) float f32x4;
typedef __attribute__((ext_vector_type(4))) unsigned uint4v;

#define MFMA_BF16 __builtin_amdgcn_mfma_f32_16x16x32_bf16

__device__ __forceinline__ short f2bf(float f) {
  union { float f; unsigned u; } v; v.f = f;
  unsigned r = v.u + 0x7FFFu + ((v.u >> 16) & 1u);
  return (short)(r >> 16);
}
__device__ __forceinline__ unsigned cvtpk(float lo, float hi) {
  unsigned r;
  asm("v_cvt_pk_bf16_f32 %0, %1, %2" : "=v"(r) : "v"(lo), "v"(hi));
  return r;
}
// async 16B global->LDS (lane i writes lds_base + i*16)
__device__ __forceinline__ void gll16(const void* g, void* l) {
  __builtin_amdgcn_global_load_lds(
      (const __attribute__((address_space(1))) void*)g,
      (__attribute__((address_space(3))) void*)l, 16, 0, 0);
}

// Counted-vmcnt pipelined barriers (allow next tile's loads to stay in flight).
__device__ __forceinline__ void pipe_barrier6() {   // gemm1: 2 gll + 4 loads/iter
  __builtin_amdgcn_sched_barrier(0);
  asm volatile("s_waitcnt vmcnt(6) lgkmcnt(0)" ::: "memory");
  __builtin_amdgcn_s_barrier();
  __builtin_amdgcn_sched_barrier(0);
}
__device__ __forceinline__ void pipe_barrier4() {   // gemm2: 2 gll + 2 loads/iter
  __builtin_amdgcn_sched_barrier(0);
  asm volatile("s_waitcnt vmcnt(4) lgkmcnt(0)" ::: "memory");
  __builtin_amdgcn_s_barrier();
  __builtin_amdgcn_sched_barrier(0);
}
__device__ __forceinline__ void drain_barrier() {
  __builtin_amdgcn_sched_barrier(0);
  asm volatile("s_waitcnt vmcnt(0) lgkmcnt(0)" ::: "memory");
  __builtin_amdgcn_s_barrier();
  __builtin_amdgcn_sched_barrier(0);
}

// B-tile swizzle (unchanged, read-verified at floor): rows of 64B.
__device__ __forceinline__ unsigned bswz(int n, int kbyte) {
  return (unsigned)(n * 64 + (kbyte ^ (((n >> 2) & 3) << 4)));
}
// A-tile read swizzle: byte(r,kbyte) = r*64 + (kbyte ^ (((r>>1)&3)<<4)).
// Writes are linear (global_load_lds) with the INVERSE applied to the per-lane
// global source address; reads enumerate to 2 lanes/bank (free, m136).
__device__ __forceinline__ unsigned aswz(int r, int kbyte) {
  return (unsigned)(r * 64 + (kbyte ^ (((r >> 1) & 3) << 4)));
}

// ---------------------------------------------------------------------------
// Kernel 0: hs f32 -> bf16
// ---------------------------------------------------------------------------
__global__ __launch_bounds__(256) void k_prep(const float* __restrict__ hs,
                                              short* __restrict__ hs_bf) {
  int i = (blockIdx.x * 256 + threadIdx.x) * 8;
  float4 v0 = *(const float4*)&hs[i];
  float4 v1 = *(const float4*)&hs[i + 4];
  uint4v p;
  p.x = cvtpk(v0.x, v0.y); p.y = cvtpk(v0.z, v0.w);
  p.z = cvtpk(v1.x, v1.y); p.w = cvtpk(v1.z, v1.w);
  *(uint4v*)&hs_bf[i] = p;
}

// ---------------------------------------------------------------------------
// Kernel 1: slot lists + combine weights + compact chunk table
// meta[0..8]=offs, meta[9]=nchunks, meta[16+c] = e | (row0<<8)
// ---------------------------------------------------------------------------
__global__ __launch_bounds__(1024) void k_build(
    const float* __restrict__ aff, const int* __restrict__ eidx,
    int* __restrict__ meta, int* __restrict__ slot_tok, float* __restrict__ slot_w) {
  __shared__ int cnt[E_];
  __shared__ int soff[E_ + 1];
  int t = threadIdx.x;
  if (t < E_) cnt[t] = 0;
  __syncthreads();
  int e0 = eidx[t * 2 + 0];
  int e1 = eidx[t * 2 + 1];
  float a0 = aff[t * E_ + e0];
  float a1 = aff[t * E_ + e1];
  float inv = 1.0f / (a0 + a1);
  int r0 = atomicAdd(&cnt[e0], 1);
  int r1 = atomicAdd(&cnt[e1], 1);
  __syncthreads();
  if (t == 0) {
    int s = 0;
    for (int e = 0; e < E_; ++e) { soff[e] = s; s += cnt[e]; }
    soff[E_] = s;
    int nc = 0;
    for (int e = 0; e < E_; ++e)
      for (int c = soff[e]; c < soff[e] + cnt[e]; c += BM)
        meta[16 + nc++] = e | (c << 8);
    meta[9] = nc;
  }
  __syncthreads();
  if (t <= E_) meta[t] = soff[t];
  int s0 = soff[e0] + r0;
  int s1 = soff[e1] + r1;
  slot_tok[s0] = t; slot_w[s0] = a0 * inv;
  slot_tok[s1] = t; slot_w[s1] = a1 * inv;
}

// ---------------------------------------------------------------------------
// Kernel 2: grouped GEMM  act[slot,i] = silu(X@Wg) * (X@Wu)
// 256 thr (4 waves, 4m x 1n), tile 128x32, depth-2 counted-vmcnt pipeline,
// sA ring-4 via source-swizzled gll, sB ring-2 via cvt_pk staging.
// ---------------------------------------------------------------------------
__global__ __launch_bounds__(256, 4) void k_gemm1(
    const short* __restrict__ hs_bf, const float* __restrict__ wg,
    const float* __restrict__ wu, const int* __restrict__ meta,
    const int* __restrict__ slot_tok, short* __restrict__ act) {
  int nch = meta[9];
  int yc = blockIdx.y;
  if (yc >= nch) return;
  int ck = meta[16 + yc];
  int e = ck & 255;
  int row0 = ck >> 8;
  int rows = min(BM, meta[1 + e] - row0);
  int i0 = blockIdx.x * BN;

  __shared__ short sA[4][BM * BK];       // 32KB, ring-4, swizzled rows of 64B
  __shared__ short sB[2][2][BN * BK];    // 8KB, ring-2 x {gate,up}

  int tid = threadIdx.x;
  int lane = tid & 63;
  int w = tid >> 6;                 // 0..3 = wm
  int lr = lane & 15;
  int q = lane >> 4;
  int lk = q * 8;

  const float* wgE = wg + (size_t)e * H_ * I_;
  const float* wuE = wu + (size_t)e * H_ * I_;

  // A gll: wave w stages rows 32w..32w+31 with 2 glls (16 rows each).
  // Inverse swizzle on the global source k-slot: kg = (lane&3) ^ ((lane>>3)&3).
  int r1 = 32 * w + (lane >> 2);
  int kgel = ((lane & 3) ^ ((lane >> 3) & 3)) * 8;   // element offset 0..24
  int tok1 = slot_tok[row0 + min(r1, rows - 1)];
  int tok2 = slot_tok[row0 + min(r1 + 16, rows - 1)];
  const short* srcA1 = hs_bf + (size_t)tok1 * H_ + kgel;
  const short* srcA2 = hs_bf + (size_t)tok2 * H_ + kgel;

  // B: thread owns k-pair up=tid>>4, n-pair n2=(tid&15)*2, both mats.
  int up = tid >> 4;
  int n2 = (tid & 15) * 2;
  const float* srcBg = wgE + (size_t)(2 * up) * I_ + i0 + n2;
  const float* srcBu = wuE + (size_t)(2 * up) * I_ + i0 + n2;

  f32x4 accg[2][2], accu[2][2];
#pragma unroll
  for (int mr = 0; mr < 2; ++mr)
#pragma unroll
    for (int nr = 0; nr < 2; ++nr) {
      accg[mr][nr] = (f32x4){0.f, 0.f, 0.f, 0.f};
      accu[mr][nr] = (f32x4){0.f, 0.f, 0.f, 0.f};
    }

  float2 bg[2][2], bu[2][2];   // [set][k-row of pair]

  // ---- prologue: tiles 0,1 in flight; convert tile 0; drain once ----
  gll16(srcA1, &sA[0][w * 1024]);
  gll16(srcA2, &sA[0][w * 1024 + 512]);
  bg[0][0] = *(const float2*)srcBg;
  bg[0][1] = *(const float2*)(srcBg + I_);
  bu[0][0] = *(const float2*)srcBu;
  bu[0][1] = *(const float2*)(srcBu + I_);
  gll16(srcA1 + BK, &sA[1][w * 1024]);
  gll16(srcA2 + BK, &sA[1][w * 1024 + 512]);
  bg[1][0] = *(const float2*)(srcBg + (size_t)BK * I_);
  bg[1][1] = *(const float2*)(srcBg + (size_t)(BK + 1) * I_);
  bu[1][0] = *(const float2*)(srcBu + (size_t)BK * I_);
  bu[1][1] = *(const float2*)(srcBu + (size_t)(BK + 1) * I_);
  *(unsigned*)((char*)&sB[0][0][0] + bswz(n2, 4 * up))     = cvtpk(bg[0][0].x, bg[0][1].x);
  *(unsigned*)((char*)&sB[0][0][0] + bswz(n2 + 1, 4 * up)) = cvtpk(bg[0][0].y, bg[0][1].y);
  *(unsigned*)((char*)&sB[0][1][0] + bswz(n2, 4 * up))     = cvtpk(bu[0][0].x, bu[0][1].x);
  *(unsigned*)((char*)&sB[0][1][0] + bswz(n2 + 1, 4 * up)) = cvtpk(bu[0][0].y, bu[0][1].y);
  drain_barrier();

  const int NT = H_ / BK;   // 32

#define G1_ITER(U, base_) do {                                                 \
    int t_ = (base_) + (U);                                                    \
    if (t_ + 2 < NT) {                                                         \
      int k2 = (t_ + 2) * BK;                                                  \
      gll16(srcA1 + k2, &sA[((U) + 2) & 3][w * 1024]);                         \
      gll16(srcA2 + k2, &sA[((U) + 2) & 3][w * 1024 + 512]);                   \
      bg[(U) & 1][0] = *(const float2*)(srcBg + (size_t)k2 * I_);              \
      bg[(U) & 1][1] = *(const float2*)(srcBg + (size_t)(k2 + 1) * I_);        \
      bu[(U) & 1][0] = *(const float2*)(srcBu + (size_t)k2 * I_);              \
      bu[(U) & 1][1] = *(const float2*)(srcBu + (size_t)(k2 + 1) * I_);        \
    }                                                                          \
    bf16x8 a0 = *(const bf16x8*)((const char*)&sA[(U)][0]                      \
                                 + aswz(w * 32 + lr, lk * 2));                 \
    bf16x8 a1 = *(const bf16x8*)((const char*)&sA[(U)][0]                      \
                                 + aswz(w * 32 + 16 + lr, lk * 2));            \
    unsigned off0 = bswz(lr, lk * 2);                                          \
    unsigned off1 = bswz(16 + lr, lk * 2);                                     \
    bf16x8 fg0 = *(const bf16x8*)((const char*)&sB[(U) & 1][0][0] + off0);     \
    bf16x8 fg1 = *(const bf16x8*)((const char*)&sB[(U) & 1][0][0] + off1);     \
    bf16x8 fu0 = *(const bf16x8*)((const char*)&sB[(U) & 1][1][0] + off0);     \
    bf16x8 fu1 = *(const bf16x8*)((const char*)&sB[(U) & 1][1][0] + off1);     \
    accg[0][0] = MFMA_BF16(a0, fg0, accg[0][0], 0, 0, 0);                      \
    accg[0][1] = MFMA_BF16(a0, fg1, accg[0][1], 0, 0, 0);                      \
    accg[1][0] = MFMA_BF16(a1, fg0, accg[1][0], 0, 0, 0);                      \
    accg[1][1] = MFMA_BF16(a1, fg1, accg[1][1], 0, 0, 0);                      \
    accu[0][0] = MFMA_BF16(a0, fu0, accu[0][0], 0, 0, 0);                      \
    accu[0][1] = MFMA_BF16(a0, fu1, accu[0][1], 0, 0, 0);                      \
    accu[1][0] = MFMA_BF16(a1, fu0, accu[1][0], 0, 0, 0);                      \
    accu[1][1] = MFMA_BF16(a1, fu1, accu[1][1], 0, 0, 0);                      \
    if (t_ + 1 < NT) {                                                         \
      int s_ = ((U) + 1) & 1;                                                  \
      *(unsigned*)((char*)&sB[s_][0][0] + bswz(n2, 4 * up))                    \
          = cvtpk(bg[s_][0].x, bg[s_][1].x);                                   \
      *(unsigned*)((char*)&sB[s_][0][0] + bswz(n2 + 1, 4 * up))                \
          = cvtpk(bg[s_][0].y, bg[s_][1].y);                                   \
      *(unsigned*)((char*)&sB[s_][1][0] + bswz(n2, 4 * up))                    \
          = cvtpk(bu[s_][0].x, bu[s_][1].x);                                   \
      *(unsigned*)((char*)&sB[s_][1][0] + bswz(n2 + 1, 4 * up))                \
          = cvtpk(bu[s_][0].y, bu[s_][1].y);                                   \
    }                                                                          \
    pipe_barrier6();                                                           \
  } while (0)

  for (int base = 0; base < NT; base += 4) {
    G1_ITER(0, base);
    G1_ITER(1, base);
    G1_ITER(2, base);
    G1_ITER(3, base);
  }
#undef G1_ITER

  // ---- epilogue: silu(g)*u -> bf16 act ----
#pragma unroll
  for (int mr = 0; mr < 2; ++mr) {
#pragma unroll
    for (int r = 0; r < 4; ++r) {
      int m = w * 32 + mr * 16 + q * 4 + r;
      if (m < rows) {
#pragma unroll
        for (int nr = 0; nr < 2; ++nr) {
          float g = accg[mr][nr][r];
          float u = accu[mr][nr][r];
          float sg = 1.0f / (1.0f + __expf(-g));
          act[(size_t)(row0 + m) * I_ + i0 + nr * 16 + lr] = f2bf(g * sg * u);
        }
      }
    }
  }
}

// ---------------------------------------------------------------------------
// Kernel 3: grouped GEMM  out[tok,h] += w * (act[slot,:] @ Wd[e]); split-K x2
// ---------------------------------------------------------------------------
__global__ __launch_bounds__(256, 4) void k_gemm2(
    const short* __restrict__ act, const float* __restrict__ wd,
    const int* __restrict__ meta, const int* __restrict__ slot_tok,
    const float* __restrict__ slot_w, float* __restrict__ out) {
  int nch = meta[9];
  int yc = blockIdx.y;
  if (yc >= nch) return;
  int ck = meta[16 + yc];
  int e = ck & 255;
  int row0 = ck >> 8;
  int rows = min(BM, meta[1 + e] - row0);
  int h0 = blockIdx.x * BN;
  int kbase = blockIdx.z * (I_ / SPLITK2);

  __shared__ short sA[4][BM * BK];   // 32KB ring-4, swizzled
  __shared__ short sB[2][BN * BK];   // 4KB ring-2

  int tid = threadIdx.x;
  int lane = tid & 63;
  int w = tid >> 6;
  int lr = lane & 15;
  int q = lane >> 4;
  int lk = q * 8;

  const float* wdE = wd + (size_t)e * I_ * H_;

  int r1 = 32 * w + (lane >> 2);
  int kgel = ((lane & 3) ^ ((lane >> 3) & 3)) * 8;
  const short* srcA1 = act + (size_t)(row0 + min(r1, rows - 1)) * I_ + kbase + kgel;
  const short* srcA2 = act + (size_t)(row0 + min(r1 + 16, rows - 1)) * I_ + kbase + kgel;

  int up = tid >> 4;
  int n2 = (tid & 15) * 2;
  const float* srcB = wdE + (size_t)(kbase + 2 * up) * H_ + h0 + n2;

  f32x4 acc[2][2];
#pragma unroll
  for (int mr = 0; mr < 2; ++mr)
#pragma unroll
    for (int nr = 0; nr < 2; ++nr)
      acc[mr][nr] = (f32x4){0.f, 0.f, 0.f, 0.f};

  float2 bd[2][2];

  // prologue
  gll16(srcA1, &sA[0][w * 1024]);
  gll16(srcA2, &sA[0][w * 1024 + 512]);
  bd[0][0] = *(const float2*)srcB;
  bd[0][1] = *(const float2*)(srcB + H_);
  gll16(srcA1 + BK, &sA[1][w * 1024]);
  gll16(srcA2 + BK, &sA[1][w * 1024 + 512]);
  bd[1][0] = *(const float2*)(srcB + (size_t)BK * H_);
  bd[1][1] = *(const float2*)(srcB + (size_t)(BK + 1) * H_);
  *(unsigned*)((char*)&sB[0][0] + bswz(n2, 4 * up))     = cvtpk(bd[0][0].x, bd[0][1].x);
  *(unsigned*)((char*)&sB[0][0] + bswz(n2 + 1, 4 * up)) = cvtpk(bd[0][0].y, bd[0][1].y);
  drain_barrier();

  const int NT = (I_ / SPLITK2) / BK;   // 32

#define G2_ITER(U, base_) do {                                                 \
    int t_ = (base_) + (U);                                                    \
    if (t_ + 2 < NT) {                                                         \
      int k2 = (t_ + 2) * BK;                                                  \
      gll16(srcA1 + k2, &sA[((U) + 2) & 3][w * 1024]);                         \
      gll16(srcA2 + k2, &sA[((U) + 2) & 3][w * 1024 + 512]);                   \
      bd[(U) & 1][0] = *(const float2*)(srcB + (size_t)k2 * H_);               \
      bd[(U) & 1][1] = *(const float2*)(srcB + (size_t)(k2 + 1) * H_);         \
    }                                                                          \
    bf16x8 a0 = *(const bf16x8*)((const char*)&sA[(U)][0]                      \
                                 + aswz(w * 32 + lr, lk * 2));                 \
    bf16x8 a1 = *(const bf16x8*)((const char*)&sA[(U)][0]                      \
                                 + aswz(w * 32 + 16 + lr, lk * 2));            \
    bf16x8 b0 = *(const bf16x8*)((const char*)&sB[(U) & 1][0]                  \
                                 + bswz(lr, lk * 2));                          \
    bf16x8 b1 = *(const bf16x8*)((const char*)&sB[(U) & 1][0]                  \
                                 + bswz(16 + lr, lk * 2));                     \
    acc[0][0] = MFMA_BF16(a0, b0, acc[0][0], 0, 0, 0);                         \
    acc[0][1] = MFMA_BF16(a0, b1, acc[0][1], 0, 0, 0);                         \
    acc[1][0] = MFMA_BF16(a1, b0, acc[1][0], 0, 0, 0);                         \
    acc[1][1] = MFMA_BF16(a1, b1, acc[1][1], 0, 0, 0);                         \
    if (t_ + 1 < NT) {                                                         \
      int s_ = ((U) + 1) & 1;                                                  \
      *(unsigned*)((char*)&sB[s_][0] + bswz(n2, 4 * up))                       \
          = cvtpk(bd[s_][0].x, bd[s_][1].x);                                   \
      *(unsigned*)((char*)&sB[s_][0] + bswz(n2 + 1, 4 * up))                   \
          = cvtpk(bd[s_][0].y, bd[s_][1].y);                                   \
    }                                                                          \
    pipe_barrier4();                                                           \
  } while (0)

  for (int base = 0; base < NT; base += 4) {
    G2_ITER(0, base);
    G2_ITER(1, base);
    G2_ITER(2, base);
    G2_ITER(3, base);
  }
#undef G2_ITER

  // epilogue: scale by combine weight, scatter-add
#pragma unroll
  for (int mr = 0; mr < 2; ++mr) {
#pragma unroll
    for (int r = 0; r < 4; ++r) {
      int m = w * 32 + mr * 16 + q * 4 + r;
      if (m < rows) {
        int gs = row0 + m;
        float wc = slot_w[gs];
        int tok = slot_tok[gs];
#pragma unroll
        for (int nr = 0; nr < 2; ++nr)
          atomicAdd(&out[(size_t)tok * H_ + h0 + nr * 16 + lr],
                    acc[mr][nr][r] * wc);
      }
    }
  }
}

// ---------------------------------------------------------------------------
extern "C" void kernel_launch(void* const* d_in, const int* in_sizes, int n_in,
                              void* d_out, int out_size, void* d_ws, size_t ws_size,
                              hipStream_t stream) {
  const float* hs   = (const float*)d_in[0];
  const float* aff  = (const float*)d_in[1];
  const int*   eidx = (const int*)d_in[2];
  const float* wg   = (const float*)d_in[3];
  const float* wu   = (const float*)d_in[4];
  const float* wd   = (const float*)d_in[5];
  float* out = (float*)d_out;

  char* ws = (char*)d_ws;
  int*   meta     = (int*)ws;                            // 256B reserved
  int*   slot_tok = (int*)(ws + 256);                    // 2048 ints
  float* slot_w   = (float*)(ws + 256 + NSLOT * 4);      // 2048 floats
  short* hs_bf    = (short*)(ws + 256 + NSLOT * 8);      // 2MB bf16 hs
  short* act      = (short*)(ws + 256 + NSLOT * 8 + (size_t)T_ * H_ * 2);  // 8MB

  hipMemsetAsync(d_out, 0, (size_t)out_size * sizeof(float), stream);
  k_build<<<1, T_, 0, stream>>>(aff, eidx, meta, slot_tok, slot_w);
  k_prep<<<(T_ * H_) / (256 * 8), 256, 0, stream>>>(hs, hs_bf);
  k_gemm1<<<dim3(I_ / BN, NCHUNK_CAP), 256, 0, stream>>>(hs_bf, wg, wu, meta, slot_tok, act);
  k_gemm2<<<dim3(H_ / BN, NCHUNK_CAP, SPLITK2), 256, 0, stream>>>(act, wd, meta, slot_tok, slot_w, out);
}

// Round 6
// 102.226 us; speedup vs baseline: 1.1977x; 1.1977x over previous
//
#include <hip/hip_runtime.h>
#include <hip/hip_bf16.h>
#include <math.h>

// Problem constants (fixed shape)
#define T_ 1024
#define H_ 1024
#define I_ 2048
#define E_ 8
#define NSLOT 2048

// GEMM tiling
#define BM 128
#define BN 64
#define BK 32
#define NCHUNK_CAP 24               // sum ceil(cnt_e/BM) <= 23
#define SPLITK2 2                    // gemm2 split-K (I=2048 -> 2x1024)

typedef __attribute__((ext_vector_type(8))) short bf16x8;
typedef __attribute__((ext_vector_type(4))) float f32x4;
typedef __attribute__((ext_vector_type(4))) unsigned uint4v;

#define MFMA_BF16 __builtin_amdgcn_mfma_f32_16x16x32_bf16

__device__ __forceinline__ short f2bf(float f) {
  union { float f; unsigned u; } v; v.f = f;
  unsigned r = v.u + 0x7FFFu + ((v.u >> 16) & 1u);
  return (short)(r >> 16);
}
__device__ __forceinline__ unsigned cvtpk(float lo, float hi) {
  unsigned r;
  asm("v_cvt_pk_bf16_f32 %0, %1, %2" : "=v"(r) : "v"(lo), "v"(hi));
  return r;
}
// async 16B global->LDS (lane i writes lds_base + i*16)
__device__ __forceinline__ void gll16(const void* g, void* l) {
  __builtin_amdgcn_global_load_lds(
      (const __attribute__((address_space(1))) void*)g,
      (__attribute__((address_space(3))) void*)l, 16, 0, 0);
}

// Counted-vmcnt pipelined barrier. Per-thread VMEM issue rate = 3/iter
// (1 gll + 2 reg loads); pipeline depth 3 => steady-state 2 newer iters
// in flight across the barrier => vmcnt(6). lgkmcnt(0) drains own ds ops.
__device__ __forceinline__ void pipe_barrier6() {
  __builtin_amdgcn_sched_barrier(0);
  asm volatile("s_waitcnt vmcnt(6) lgkmcnt(0)" ::: "memory");
  __builtin_amdgcn_s_barrier();
  __builtin_amdgcn_sched_barrier(0);
}
__device__ __forceinline__ void drain_barrier() {
  __builtin_amdgcn_sched_barrier(0);
  asm volatile("s_waitcnt vmcnt(0) lgkmcnt(0)" ::: "memory");
  __builtin_amdgcn_s_barrier();
  __builtin_amdgcn_sched_barrier(0);
}

// Swizzled [n][k] bf16 B-tile: rows of 64B (BK=32 bf16).
__device__ __forceinline__ unsigned bswz(int n, int kbyte) {
  return (unsigned)(n * 64 + (kbyte ^ (((n >> 2) & 3) << 4)));
}

// ---------------------------------------------------------------------------
// Kernel 0: hs f32 -> bf16
// ---------------------------------------------------------------------------
__global__ __launch_bounds__(256) void k_prep(const float* __restrict__ hs,
                                              short* __restrict__ hs_bf) {
  int i = (blockIdx.x * 256 + threadIdx.x) * 8;
  float4 v0 = *(const float4*)&hs[i];
  float4 v1 = *(const float4*)&hs[i + 4];
  uint4v p;
  p.x = cvtpk(v0.x, v0.y); p.y = cvtpk(v0.z, v0.w);
  p.z = cvtpk(v1.x, v1.y); p.w = cvtpk(v1.z, v1.w);
  *(uint4v*)&hs_bf[i] = p;
}

// ---------------------------------------------------------------------------
// Kernel 1: slot lists + combine weights + compact chunk table
// meta[0..8]=offs, meta[9]=nchunks, meta[16+c] = e | (row0<<8)
// ---------------------------------------------------------------------------
__global__ __launch_bounds__(1024) void k_build(
    const float* __restrict__ aff, const int* __restrict__ eidx,
    int* __restrict__ meta, int* __restrict__ slot_tok, float* __restrict__ slot_w) {
  __shared__ int cnt[E_];
  __shared__ int soff[E_ + 1];
  int t = threadIdx.x;
  if (t < E_) cnt[t] = 0;
  __syncthreads();
  int e0 = eidx[t * 2 + 0];
  int e1 = eidx[t * 2 + 1];
  float a0 = aff[t * E_ + e0];
  float a1 = aff[t * E_ + e1];
  float inv = 1.0f / (a0 + a1);
  int r0 = atomicAdd(&cnt[e0], 1);
  int r1 = atomicAdd(&cnt[e1], 1);
  __syncthreads();
  if (t == 0) {
    int s = 0;
    for (int e = 0; e < E_; ++e) { soff[e] = s; s += cnt[e]; }
    soff[E_] = s;
    int nc = 0;
    for (int e = 0; e < E_; ++e)
      for (int c = soff[e]; c < soff[e] + cnt[e]; c += BM)
        meta[16 + nc++] = e | (c << 8);
    meta[9] = nc;
  }
  __syncthreads();
  if (t <= E_) meta[t] = soff[t];
  int s0 = soff[e0] + r0;
  int s1 = soff[e1] + r1;
  slot_tok[s0] = t; slot_w[s0] = a0 * inv;
  slot_tok[s1] = t; slot_w[s1] = a1 * inv;
}

// ---------------------------------------------------------------------------
// Kernel 2: grouped GEMM  act[slot,i] = silu(X@Wg) * (X@Wu)
// 512 thr (8 waves, 4m x 2n). Depth-3 pipeline: A gll ring-4 (issue t+3),
// B reg ring-4 (issue t+3, convert t+1 => load->use = 2 iters), vmcnt(6).
// ---------------------------------------------------------------------------
__global__ __launch_bounds__(512, 4) void k_gemm1(
    const short* __restrict__ hs_bf, const float* __restrict__ wg,
    const float* __restrict__ wu, const int* __restrict__ meta,
    const int* __restrict__ slot_tok, short* __restrict__ act) {
  int nch = meta[9];
  int yc = blockIdx.y;
  if (yc >= nch) return;
  int ck = meta[16 + yc];
  int e = ck & 255;
  int row0 = ck >> 8;
  int rows = min(BM, meta[1 + e] - row0);
  int i0 = blockIdx.x * BN;

  __shared__ short sA[4][BM * BK];       // 32KB ring-4, [row][k] 64B rows
  __shared__ short sB[2][2][BN * BK];    // 16KB ring-2 x {gate,up}, swizzled

  int tid = threadIdx.x;
  int lane = tid & 63;
  int w = tid >> 6;                 // 0..7
  int wm = w >> 1, wn = w & 1;      // 4m x 2n
  int lr = lane & 15;
  int lk = (lane >> 4) * 8;

  const float* wgE = wg + (size_t)e * H_ * I_;
  const float* wuE = wu + (size_t)e * H_ * I_;

  // A gll: wave w stages rows [16w,16w+16)
  int ra = 16 * w + (lane >> 2);
  int tokA = slot_tok[row0 + min(ra, rows - 1)];
  const short* srcA = hs_bf + (size_t)tokA * H_ + (lane & 3) * 8;
  // B: waves 0-3 stage gate, 4-7 up; per thread 1 k-pair x 4 n
  const float* wB = (w < 4) ? wgE : wuE;
  int mat = (w >= 4);
  int up = 4 * (w & 3) + (lane >> 4);   // k-pair 0..15
  int n4 = (lane & 15) * 4;
  const float* srcB = wB + (size_t)(2 * up) * I_ + i0 + n4;

  f32x4 accg[2][2], accu[2][2];
#pragma unroll
  for (int mr = 0; mr < 2; ++mr)
#pragma unroll
    for (int nr = 0; nr < 2; ++nr) {
      accg[mr][nr] = (f32x4){0.f, 0.f, 0.f, 0.f};
      accu[mr][nr] = (f32x4){0.f, 0.f, 0.f, 0.f};
    }

  float4 bs[4][2];   // B reg ring-4 (tile index & 3), static-indexed

  // ---- prologue: tiles 0,1,2 in flight; convert tile 0; drain once ----
#pragma unroll
  for (int p = 0; p < 3; ++p) {
    gll16(srcA + p * BK, &sA[p][w * 512]);
    bs[p][0] = *(const float4*)(srcB + (size_t)(p * BK) * I_);
    bs[p][1] = *(const float4*)(srcB + (size_t)(p * BK + 1) * I_);
  }
  {
    const float* p0 = (const float*)&bs[0][0];
    const float* p1 = (const float*)&bs[0][1];
#pragma unroll
    for (int j = 0; j < 4; ++j)
      *(unsigned*)((char*)&sB[0][mat][0] + bswz(n4 + j, 4 * up)) = cvtpk(p0[j], p1[j]);
  }
  drain_barrier();

  const int NT = H_ / BK;   // 32

#define G1_ITER(U, base_) do {                                                 \
    int t_ = (base_) + (U);                                                    \
    if (t_ + 3 < NT) {                                                         \
      int k3 = (t_ + 3) * BK;                                                  \
      gll16(srcA + k3, &sA[((U) + 3) & 3][w * 512]);                           \
      bs[((U) + 3) & 3][0] = *(const float4*)(srcB + (size_t)k3 * I_);         \
      bs[((U) + 3) & 3][1] = *(const float4*)(srcB + (size_t)(k3 + 1) * I_);   \
    }                                                                          \
    bf16x8 a0 = *(const bf16x8*)&sA[(U)][(wm * 32 + lr) * BK + lk];            \
    bf16x8 a1 = *(const bf16x8*)&sA[(U)][(wm * 32 + 16 + lr) * BK + lk];       \
    unsigned off0 = bswz(wn * 32 + lr, lk * 2);                                \
    unsigned off1 = bswz(wn * 32 + 16 + lr, lk * 2);                           \
    bf16x8 bg0 = *(const bf16x8*)((const char*)&sB[(U) & 1][0][0] + off0);     \
    bf16x8 bg1 = *(const bf16x8*)((const char*)&sB[(U) & 1][0][0] + off1);     \
    bf16x8 bu0 = *(const bf16x8*)((const char*)&sB[(U) & 1][1][0] + off0);     \
    bf16x8 bu1 = *(const bf16x8*)((const char*)&sB[(U) & 1][1][0] + off1);     \
    accg[0][0] = MFMA_BF16(a0, bg0, accg[0][0], 0, 0, 0);                      \
    accg[0][1] = MFMA_BF16(a0, bg1, accg[0][1], 0, 0, 0);                      \
    accg[1][0] = MFMA_BF16(a1, bg0, accg[1][0], 0, 0, 0);                      \
    accg[1][1] = MFMA_BF16(a1, bg1, accg[1][1], 0, 0, 0);                      \
    accu[0][0] = MFMA_BF16(a0, bu0, accu[0][0], 0, 0, 0);                      \
    accu[0][1] = MFMA_BF16(a0, bu1, accu[0][1], 0, 0, 0);                      \
    accu[1][0] = MFMA_BF16(a1, bu0, accu[1][0], 0, 0, 0);                      \
    accu[1][1] = MFMA_BF16(a1, bu1, accu[1][1], 0, 0, 0);                      \
    if (t_ + 1 < NT) {                                                         \
      const float* p0 = (const float*)&bs[((U) + 1) & 3][0];                   \
      const float* p1 = (const float*)&bs[((U) + 1) & 3][1];                   \
      _Pragma("unroll")                                                        \
      for (int j = 0; j < 4; ++j)                                              \
        *(unsigned*)((char*)&sB[((U) + 1) & 1][mat][0] + bswz(n4 + j, 4 * up)) \
            = cvtpk(p0[j], p1[j]);                                             \
    }                                                                          \
    pipe_barrier6();                                                           \
  } while (0)

  for (int base = 0; base < NT; base += 4) {
    G1_ITER(0, base);
    G1_ITER(1, base);
    G1_ITER(2, base);
    G1_ITER(3, base);
  }
#undef G1_ITER

  // ---- epilogue: silu(g)*u -> bf16 act ----
#pragma unroll
  for (int mr = 0; mr < 2; ++mr) {
#pragma unroll
    for (int r = 0; r < 4; ++r) {
      int m = wm * 32 + mr * 16 + (lane >> 4) * 4 + r;
      if (m < rows) {
#pragma unroll
        for (int nr = 0; nr < 2; ++nr) {
          float g = accg[mr][nr][r];
          float u = accu[mr][nr][r];
          float sg = 1.0f / (1.0f + __expf(-g));
          act[(size_t)(row0 + m) * I_ + i0 + wn * 32 + nr * 16 + lr] = f2bf(g * sg * u);
        }
      }
    }
  }
}

// ---------------------------------------------------------------------------
// Kernel 3: grouped GEMM  out[tok,h] += w * (act[slot,:] @ Wd[e]); split-K x2
// Same depth-3 pipeline, vmcnt(6).
// ---------------------------------------------------------------------------
__global__ __launch_bounds__(512, 4) void k_gemm2(
    const short* __restrict__ act, const float* __restrict__ wd,
    const int* __restrict__ meta, const int* __restrict__ slot_tok,
    const float* __restrict__ slot_w, float* __restrict__ out) {
  int nch = meta[9];
  int yc = blockIdx.y;
  if (yc >= nch) return;
  int ck = meta[16 + yc];
  int e = ck & 255;
  int row0 = ck >> 8;
  int rows = min(BM, meta[1 + e] - row0);
  int h0 = blockIdx.x * BN;
  int kbase = blockIdx.z * (I_ / SPLITK2);

  __shared__ short sA[4][BM * BK];   // ring-4
  __shared__ short sB[2][BN * BK];   // ring-2, swizzled [n][k]

  int tid = threadIdx.x;
  int lane = tid & 63;
  int w = tid >> 6;
  int wm = w >> 1, wn = w & 1;
  int lr = lane & 15;
  int lk = (lane >> 4) * 8;

  const float* wdE = wd + (size_t)e * I_ * H_;

  int ra = min(16 * w + (lane >> 2), rows - 1);
  const short* srcA = act + (size_t)(row0 + ra) * I_ + kbase + (lane & 3) * 8;
  int up = tid >> 5;                   // k-pair 0..15
  int n2 = (tid & 31) * 2;
  const float* srcB = wdE + (size_t)(kbase + 2 * up) * H_ + h0 + n2;

  f32x4 acc[2][2];
#pragma unroll
  for (int mr = 0; mr < 2; ++mr)
#pragma unroll
    for (int nr = 0; nr < 2; ++nr)
      acc[mr][nr] = (f32x4){0.f, 0.f, 0.f, 0.f};

  float2 bs[4][2];   // B reg ring-4

  // prologue: tiles 0,1,2
#pragma unroll
  for (int p = 0; p < 3; ++p) {
    gll16(srcA + p * BK, &sA[p][w * 512]);
    bs[p][0] = *(const float2*)(srcB + (size_t)(p * BK) * H_);
    bs[p][1] = *(const float2*)(srcB + (size_t)(p * BK + 1) * H_);
  }
  *(unsigned*)((char*)&sB[0][0] + bswz(n2, 4 * up))     = cvtpk(bs[0][0].x, bs[0][1].x);
  *(unsigned*)((char*)&sB[0][0] + bswz(n2 + 1, 4 * up)) = cvtpk(bs[0][0].y, bs[0][1].y);
  drain_barrier();

  const int NT = (I_ / SPLITK2) / BK;   // 32

#define G2_ITER(U, base_) do {                                                 \
    int t_ = (base_) + (U);                                                    \
    if (t_ + 3 < NT) {                                                         \
      int k3 = (t_ + 3) * BK;                                                  \
      gll16(srcA + k3, &sA[((U) + 3) & 3][w * 512]);                           \
      bs[((U) + 3) & 3][0] = *(const float2*)(srcB + (size_t)k3 * H_);         \
      bs[((U) + 3) & 3][1] = *(const float2*)(srcB + (size_t)(k3 + 1) * H_);   \
    }                                                                          \
    bf16x8 a0 = *(const bf16x8*)&sA[(U)][(wm * 32 + lr) * BK + lk];            \
    bf16x8 a1 = *(const bf16x8*)&sA[(U)][(wm * 32 + 16 + lr) * BK + lk];       \
    bf16x8 b0 = *(const bf16x8*)((const char*)&sB[(U) & 1][0]                  \
                                 + bswz(wn * 32 + lr, lk * 2));                \
    bf16x8 b1 = *(const bf16x8*)((const char*)&sB[(U) & 1][0]                  \
                                 + bswz(wn * 32 + 16 + lr, lk * 2));           \
    acc[0][0] = MFMA_BF16(a0, b0, acc[0][0], 0, 0, 0);                         \
    acc[0][1] = MFMA_BF16(a0, b1, acc[0][1], 0, 0, 0);                         \
    acc[1][0] = MFMA_BF16(a1, b0, acc[1][0], 0, 0, 0);                         \
    acc[1][1] = MFMA_BF16(a1, b1, acc[1][1], 0, 0, 0);                         \
    if (t_ + 1 < NT) {                                                         \
      int s_ = ((U) + 1) & 3;                                                  \
      *(unsigned*)((char*)&sB[((U) + 1) & 1][0] + bswz(n2, 4 * up))            \
          = cvtpk(bs[s_][0].x, bs[s_][1].x);                                   \
      *(unsigned*)((char*)&sB[((U) + 1) & 1][0] + bswz(n2 + 1, 4 * up))        \
          = cvtpk(bs[s_][0].y, bs[s_][1].y);                                   \
    }                                                                          \
    pipe_barrier6();                                                           \
  } while (0)

  for (int base = 0; base < NT; base += 4) {
    G2_ITER(0, base);
    G2_ITER(1, base);
    G2_ITER(2, base);
    G2_ITER(3, base);
  }
#undef G2_ITER

  // epilogue: scale by combine weight, scatter-add
#pragma unroll
  for (int mr = 0; mr < 2; ++mr) {
#pragma unroll
    for (int r = 0; r < 4; ++r) {
      int m = wm * 32 + mr * 16 + (lane >> 4) * 4 + r;
      if (m < rows) {
        int gs = row0 + m;
        float wc = slot_w[gs];
        int tok = slot_tok[gs];
#pragma unroll
        for (int nr = 0; nr < 2; ++nr)
          atomicAdd(&out[(size_t)tok * H_ + h0 + wn * 32 + nr * 16 + lr],
                    acc[mr][nr][r] * wc);
      }
    }
  }
}

// ---------------------------------------------------------------------------
extern "C" void kernel_launch(void* const* d_in, const int* in_sizes, int n_in,
                              void* d_out, int out_size, void* d_ws, size_t ws_size,
                              hipStream_t stream) {
  const float* hs   = (const float*)d_in[0];
  const float* aff  = (const float*)d_in[1];
  const int*   eidx = (const int*)d_in[2];
  const float* wg   = (const float*)d_in[3];
  const float* wu   = (const float*)d_in[4];
  const float* wd   = (const float*)d_in[5];
  float* out = (float*)d_out;

  char* ws = (char*)d_ws;
  int*   meta     = (int*)ws;                            // 256B reserved
  int*   slot_tok = (int*)(ws + 256);                    // 2048 ints
  float* slot_w   = (float*)(ws + 256 + NSLOT * 4);      // 2048 floats
  short* hs_bf    = (short*)(ws + 256 + NSLOT * 8);      // 2MB bf16 hs
  short* act      = (short*)(ws + 256 + NSLOT * 8 + (size_t)T_ * H_ * 2);  // 8MB

  hipMemsetAsync(d_out, 0, (size_t)out_size * sizeof(float), stream);
  k_build<<<1, T_, 0, stream>>>(aff, eidx, meta, slot_tok, slot_w);
  k_prep<<<(T_ * H_) / (256 * 8), 256, 0, stream>>>(hs, hs_bf);
  k_gemm1<<<dim3(I_ / BN, NCHUNK_CAP), 512, 0, stream>>>(hs_bf, wg, wu, meta, slot_tok, act);
  k_gemm2<<<dim3(H_ / BN, NCHUNK_CAP, SPLITK2), 512, 0, stream>>>(act, wd, meta, slot_tok, slot_w, out);
}